// Round 6
// baseline (265.643 us; speedup 1.0000x reference)
//
#include <hip/hip_runtime.h>
#include <cmath>

#define IH 128
#define IW 128
#define NB 8

typedef __attribute__((ext_vector_type(8))) short bf16x8;
typedef __attribute__((ext_vector_type(4))) float f32x4;

union U4B8 { uint4 u; bf16x8 h; };

// ws layout (float slots):
//   offm  : [NB][27][IH][IW] f32      = 3538944
//   xT    : [NB][IH][IW][64] bf16     = 4194304 float slots (8388608 u16)
//   wt_dc : [9][64][64] bf16 (k,o,c)  = 18432 float slots
//   wt_om : [9][32][64] bf16 (k,o,c)  = 9216  float slots
#define OFFM_OFF 0
#define XT_OFF   3538944
#define WTDC_OFF (3538944 + 4194304)
#define WTOM_OFF (3538944 + 4194304 + 18432)

// fp32 -> bf16 bits, round-to-nearest-even
__device__ __forceinline__ unsigned short f32_to_bf16(float f) {
    unsigned int u = __float_as_uint(f);
    u += 0x7fffu + ((u >> 16) & 1u);
    return (unsigned short)(u >> 16);
}

// ---------------------------------------------------------------------------
// Kernel 0: weights -> bf16, layout [k][o][c] (B^T for MFMA b-frags)
// ---------------------------------------------------------------------------
__global__ void transpose_weights(const float* __restrict__ w_dc,
                                  const float* __restrict__ w_om,
                                  unsigned short* __restrict__ wt_dc16,
                                  unsigned short* __restrict__ wt_om16) {
    int idx = blockIdx.x * blockDim.x + threadIdx.x;
    if (idx < 9 * 64 * 64) {
        int k = idx >> 12;
        int o = (idx >> 6) & 63;
        int c = idx & 63;
        wt_dc16[idx] = f32_to_bf16(w_dc[(o * 64 + c) * 9 + k]);
    }
    if (idx < 9 * 32 * 64) {
        int k = idx >> 11;
        int o = (idx >> 6) & 31;
        int c = idx & 63;
        wt_om16[idx] = (o < 27) ? f32_to_bf16(w_om[(o * 64 + c) * 9 + k])
                                : (unsigned short)0;
    }
}

// ---------------------------------------------------------------------------
// Kernel 0b: x NCHW fp32 -> NHWC bf16 (xT[b][y][x][c])
// ---------------------------------------------------------------------------
__global__ __launch_bounds__(256) void transpose_x(
        const float* __restrict__ x, unsigned short* __restrict__ xT) {
    __shared__ float t[64 * 65];
    const int tid = threadIdx.x;
    const int blk = blockIdx.x;
    const int b = blk >> 8;
    const int rem = blk & 255;
    const int h = rem >> 1;
    const int w0 = (rem & 1) << 6;

    for (int i = tid; i < 4096; i += 256) {
        const int c = i >> 6;
        const int w = i & 63;
        t[w * 65 + c] = x[(((size_t)(b * 64 + c)) << 14) + (h << 7) + w0 + w];
    }
    __syncthreads();
    const int c2 = (tid & 31) * 2;
    ushort2* dst = (ushort2*)(xT + (((size_t)b << 20)) + ((size_t)((h << 7) + w0)) * 64 + c2);
#pragma unroll
    for (int p = 0; p < 8; ++p) {
        const int w = (tid >> 5) + p * 8;
        ushort2 u;
        u.x = f32_to_bf16(t[w * 65 + c2]);
        u.y = f32_to_bf16(t[w * 65 + c2 + 1]);
        dst[(size_t)w * 32] = u;
    }
}

// ---------------------------------------------------------------------------
// Kernel 1: conv3x3 -> offset/mask. Barrier-free, LDS-free.
// One wave = 16 px x 32 o (27 used). A-frags loaded directly from NHWC xT
// (per-lane predicated); B-frags directly from global weights (L1-hot).
// ---------------------------------------------------------------------------
__global__ __launch_bounds__(256) void conv_om_mfma(
        const unsigned short* __restrict__ xT,
        const float* __restrict__ b_om,
        const unsigned short* __restrict__ wt_om16,  // [9][32][64]
        float* __restrict__ offm) {
    const int tid = threadIdx.x;
    const int t = (blockIdx.x << 2) + (tid >> 6);   // global 16-px tile id
    const int b = t >> 10;
    const int rem = t & 1023;
    const int h = rem >> 3;
    const int w0 = (rem & 7) << 4;
    const int lane = tid & 63;
    const int ln15 = lane & 15;
    const int quad = lane >> 4;

    const unsigned short* xb = xT + ((size_t)b << 20);

    f32x4 acc[2] = {{0.f, 0.f, 0.f, 0.f}, {0.f, 0.f, 0.f, 0.f}};

#pragma unroll
    for (int k = 0; k < 9; ++k) {
        const int kh = k / 3;
        const int kw = k - kh * 3;
        const int y = h + kh - 1;
        const int xx = w0 + ln15 + kw - 1;
        U4B8 a0, a1;
        a0.u = make_uint4(0u, 0u, 0u, 0u);
        a1.u = make_uint4(0u, 0u, 0u, 0u);
        if (y >= 0 && y < IH && xx >= 0 && xx < IW) {
            const unsigned short* p = xb + (((size_t)((y << 7) + xx)) << 6) + (quad << 3);
            a0.u = *(const uint4*)p;
            a1.u = *(const uint4*)(p + 32);
        }
        const unsigned short* wk = wt_om16 + (k << 11) + (quad << 3);
#pragma unroll
        for (int ot = 0; ot < 2; ++ot) {
            U4B8 b0, b1;
            const unsigned short* base = wk + (((ot << 4) + ln15) << 6);
            b0.u = *(const uint4*)base;
            b1.u = *(const uint4*)(base + 32);
            acc[ot] = __builtin_amdgcn_mfma_f32_16x16x32_bf16(a0.h, b0.h, acc[ot], 0, 0, 0);
            acc[ot] = __builtin_amdgcn_mfma_f32_16x16x32_bf16(a1.h, b1.h, acc[ot], 0, 0, 0);
        }
    }

    // C/D layout: col(o)=lane&15, row(px)=quad*4+reg
#pragma unroll
    for (int ot = 0; ot < 2; ++ot) {
        const int o = (ot << 4) + ln15;
        if (o >= 27) continue;
        const float bias = b_om[o];
        float4 r;
        r.x = acc[ot][0] + bias;
        r.y = acc[ot][1] + bias;
        r.z = acc[ot][2] + bias;
        r.w = acc[ot][3] + bias;
        if (o >= 18) {
            r.x = 2.0f / (1.0f + __expf(-r.x));
            r.y = 2.0f / (1.0f + __expf(-r.y));
            r.z = 2.0f / (1.0f + __expf(-r.z));
            r.w = 2.0f / (1.0f + __expf(-r.w));
        }
        *(float4*)&offm[(((size_t)(b * 27 + o)) << 14) + (h << 7) + w0 + (quad << 2)] = r;
    }
}

// ---------------------------------------------------------------------------
// bilinear corner: accumulate 8+8 channels (frag0 at p, frag1 at p+32)
// ---------------------------------------------------------------------------
__device__ __forceinline__ void corner2(const unsigned short* __restrict__ p,
                                        float wgt, float* v) {
    const uint4 a = *(const uint4*)p;
    const uint4 c = *(const uint4*)(p + 32);
    unsigned int u[8] = {a.x, a.y, a.z, a.w, c.x, c.y, c.z, c.w};
#pragma unroll
    for (int i = 0; i < 8; ++i) {
        v[2 * i]     += wgt * __uint_as_float(u[i] << 16);
        v[2 * i + 1] += wgt * __uint_as_float(u[i] & 0xffff0000u);
    }
}

// ---------------------------------------------------------------------------
// Kernel 2: deformable conv. Barrier-free, LDS-free.
// One wave = 16 px x 64 o. Each lane gathers its own A-fragment channels
// (px=lane&15, ch = quad*8 / 32+quad*8); B-frags direct from global (L1-hot).
// ---------------------------------------------------------------------------
__global__ __launch_bounds__(256) void deform_mfma(
        const unsigned short* __restrict__ xT,
        const float* __restrict__ b_dc,
        const float* __restrict__ offm,              // [B][27][H][W]
        const unsigned short* __restrict__ wt_dc16,  // [9][64][64] (k,o,c)
        float* __restrict__ out) {
    const int tid = threadIdx.x;
    const int t = (blockIdx.x << 2) + (tid >> 6);
    const int b = t >> 10;
    const int rem = t & 1023;
    const int h = rem >> 3;
    const int w0 = (rem & 7) << 4;
    const int lane = tid & 63;
    const int ln15 = lane & 15;
    const int quad = lane >> 4;

    const unsigned short* xb = xT + ((size_t)b << 20);
    const float* ofb = offm + (((size_t)(b * 27)) << 14) + (h << 7) + w0 + ln15;

    f32x4 acc[4];
#pragma unroll
    for (int i = 0; i < 4; ++i) acc[i] = (f32x4){0.f, 0.f, 0.f, 0.f};

#pragma unroll
    for (int k = 0; k < 9; ++k) {
        const float offy = ofb[((size_t)(2 * k)) << 14];
        const float offx = ofb[((size_t)(2 * k + 1)) << 14];
        const float msk  = ofb[((size_t)(18 + k)) << 14];
        const int kh = k / 3;
        const int kw = k - kh * 3;
        const float py  = (float)(h + kh - 1) + offy;
        const float pxf = (float)(w0 + ln15 + kw - 1) + offx;
        const float y0f = floorf(py);
        const float x0f = floorf(pxf);
        const float fy = py - y0f;
        const float fx = pxf - x0f;
        const float wy0 = 1.0f - fy, wx0 = 1.0f - fx;
        const float vy0 = (y0f >= 0.0f && y0f <= 127.0f) ? 1.0f : 0.0f;
        const float vy1 = (y0f >= -1.0f && y0f <= 126.0f) ? 1.0f : 0.0f;
        const float vx0 = (x0f >= 0.0f && x0f <= 127.0f) ? 1.0f : 0.0f;
        const float vx1 = (x0f >= -1.0f && x0f <= 126.0f) ? 1.0f : 0.0f;
        const float w00 = wy0 * wx0 * vy0 * vx0;
        const float w01 = wy0 * fx  * vy0 * vx1;
        const float w10 = fy  * wx0 * vy1 * vx0;
        const float w11 = fy  * fx  * vy1 * vx1;
        const int y0i = min(max((int)y0f, 0), 127);
        const int y1i = min(max((int)y0f + 1, 0), 127);
        const int x0i = min(max((int)x0f, 0), 127);
        const int x1i = min(max((int)x0f + 1, 0), 127);

        float v[16];
#pragma unroll
        for (int i = 0; i < 16; ++i) v[i] = 0.0f;
        const int cofs = quad << 3;
        corner2(xb + ((((size_t)((y0i << 7) + x0i)) << 6) + cofs), w00, v);
        corner2(xb + ((((size_t)((y0i << 7) + x1i)) << 6) + cofs), w01, v);
        corner2(xb + ((((size_t)((y1i << 7) + x0i)) << 6) + cofs), w10, v);
        corner2(xb + ((((size_t)((y1i << 7) + x1i)) << 6) + cofs), w11, v);

        // pack A-frags: v[0..7] -> frag0 (ch quad*8..), v[8..15] -> frag1
        U4B8 a0, a1;
        unsigned int pk[8];
#pragma unroll
        for (int i = 0; i < 8; ++i) {
            const unsigned int lo = f32_to_bf16(v[2 * i] * msk);
            const unsigned int hi = f32_to_bf16(v[2 * i + 1] * msk);
            pk[i] = lo | (hi << 16);
        }
        a0.u = make_uint4(pk[0], pk[1], pk[2], pk[3]);
        a1.u = make_uint4(pk[4], pk[5], pk[6], pk[7]);

        const unsigned short* wk = wt_dc16 + (k << 12) + (quad << 3);
#pragma unroll
        for (int ot = 0; ot < 4; ++ot) {
            U4B8 b0, b1;
            const unsigned short* base = wk + (((ot << 4) + ln15) << 6);
            b0.u = *(const uint4*)base;
            b1.u = *(const uint4*)(base + 32);
            acc[ot] = __builtin_amdgcn_mfma_f32_16x16x32_bf16(a0.h, b0.h, acc[ot], 0, 0, 0);
            acc[ot] = __builtin_amdgcn_mfma_f32_16x16x32_bf16(a1.h, b1.h, acc[ot], 0, 0, 0);
        }
    }

    // epilogue: col(o)=lane&15, row(px)=quad*4+reg
#pragma unroll
    for (int ot = 0; ot < 4; ++ot) {
        const int o = (ot << 4) + ln15;
        const float bias = b_dc[o];
        float4 r;
        r.x = acc[ot][0] + bias;
        r.y = acc[ot][1] + bias;
        r.z = acc[ot][2] + bias;
        r.w = acc[ot][3] + bias;
        *(float4*)&out[(((size_t)(b * 64 + o)) << 14) + (h << 7) + w0 + (quad << 2)] = r;
    }
}

extern "C" void kernel_launch(void* const* d_in, const int* in_sizes, int n_in,
                              void* d_out, int out_size, void* d_ws, size_t ws_size,
                              hipStream_t stream) {
    const float* x    = (const float*)d_in[0];
    const float* w_om = (const float*)d_in[1];
    const float* b_om = (const float*)d_in[2];
    const float* w_dc = (const float*)d_in[3];
    const float* b_dc = (const float*)d_in[4];
    float* out = (float*)d_out;
    float* ws  = (float*)d_ws;

    float* offm = ws + OFFM_OFF;
    unsigned short* xT      = (unsigned short*)(ws + XT_OFF);
    unsigned short* wt_dc16 = (unsigned short*)(ws + WTDC_OFF);
    unsigned short* wt_om16 = (unsigned short*)(ws + WTOM_OFF);

    // 16-px tiles: NB*IH*(IW/16) = 8192 total, 4 waves (tiles) per block.
    const int n_tiles_blocks = NB * IH * (IW / 16) / 4;   // 2048

    transpose_weights<<<144, 256, 0, stream>>>(w_dc, w_om, wt_dc16, wt_om16);
    transpose_x<<<NB * IH * 2, 256, 0, stream>>>(x, xT);
    conv_om_mfma<<<n_tiles_blocks, 256, 0, stream>>>(xT, b_om, wt_om16, offm);
    deform_mfma<<<n_tiles_blocks, 256, 0, stream>>>(xT, b_dc, offm, wt_dc16, out);
}

// Round 7
// 189.577 us; speedup vs baseline: 1.4012x; 1.4012x over previous
//
#include <hip/hip_runtime.h>
#include <cmath>

#define IH 128
#define IW 128
#define NB 8

typedef __attribute__((ext_vector_type(8))) short bf16x8;
typedef __attribute__((ext_vector_type(4))) float f32x4;

union U4B8 { uint4 u; bf16x8 h; };

// ws layout (float slots):
//   offm  : [NB][27][IH][IW] f32      = 3538944
//   xT    : [NB][IH][IW][64] bf16     = 4194304 float slots (8388608 u16)
//   wt_dc : [9][64][64] bf16 (k,o,c)  = 18432 float slots
//   wt_om : [9][32][64] bf16 (k,o,c)  = 9216  float slots
#define OFFM_OFF 0
#define XT_OFF   3538944
#define WTDC_OFF (3538944 + 4194304)
#define WTOM_OFF (3538944 + 4194304 + 18432)

// fp32 -> bf16 bits, round-to-nearest-even
__device__ __forceinline__ unsigned short f32_to_bf16(float f) {
    unsigned int u = __float_as_uint(f);
    u += 0x7fffu + ((u >> 16) & 1u);
    return (unsigned short)(u >> 16);
}

// ---------------------------------------------------------------------------
// Kernel 0: weights -> bf16, layout [k][o][c]
// ---------------------------------------------------------------------------
__global__ void transpose_weights(const float* __restrict__ w_dc,
                                  const float* __restrict__ w_om,
                                  unsigned short* __restrict__ wt_dc16,
                                  unsigned short* __restrict__ wt_om16) {
    int idx = blockIdx.x * blockDim.x + threadIdx.x;
    if (idx < 9 * 64 * 64) {
        int k = idx >> 12;
        int o = (idx >> 6) & 63;
        int c = idx & 63;
        wt_dc16[idx] = f32_to_bf16(w_dc[(o * 64 + c) * 9 + k]);
    }
    if (idx < 9 * 32 * 64) {
        int k = idx >> 11;
        int o = (idx >> 6) & 31;
        int c = idx & 63;
        wt_om16[idx] = (o < 27) ? f32_to_bf16(w_om[(o * 64 + c) * 9 + k])
                                : (unsigned short)0;
    }
}

// ---------------------------------------------------------------------------
// Kernel 0b: x NCHW fp32 -> NHWC bf16 (xT[b][y][x][c])
// ---------------------------------------------------------------------------
__global__ __launch_bounds__(256) void transpose_x(
        const float* __restrict__ x, unsigned short* __restrict__ xT) {
    __shared__ float t[64 * 65];
    const int tid = threadIdx.x;
    const int blk = blockIdx.x;
    const int b = blk >> 8;
    const int rem = blk & 255;
    const int h = rem >> 1;
    const int w0 = (rem & 1) << 6;

    for (int i = tid; i < 4096; i += 256) {
        const int c = i >> 6;
        const int w = i & 63;
        t[w * 65 + c] = x[(((size_t)(b * 64 + c)) << 14) + (h << 7) + w0 + w];
    }
    __syncthreads();
    const int c2 = (tid & 31) * 2;
    ushort2* dst = (ushort2*)(xT + (((size_t)b << 20)) + ((size_t)((h << 7) + w0)) * 64 + c2);
#pragma unroll
    for (int p = 0; p < 8; ++p) {
        const int w = (tid >> 5) + p * 8;
        ushort2 u;
        u.x = f32_to_bf16(t[w * 65 + c2]);
        u.y = f32_to_bf16(t[w * 65 + c2 + 1]);
        dst[(size_t)w * 32] = u;
    }
}

// ---------------------------------------------------------------------------
// Kernel 1: conv3x3 -> offset/mask. Block = 64px x 32o, 4 waves (16px each).
// Window staged once; weights double-buffered in LDS, ONE barrier per k.
// ---------------------------------------------------------------------------
__global__ __launch_bounds__(256) void conv_om_mfma(
        const unsigned short* __restrict__ xT,
        const float* __restrict__ b_om,
        const unsigned short* __restrict__ wt_om16,  // [9][32][64]
        float* __restrict__ offm) {
    __shared__ __align__(16) unsigned short win[198 * 72];   // [3*66][72]
    __shared__ __align__(16) unsigned short wks[2][32 * 72]; // [buf][o][72]

    const int tid = threadIdx.x;
    const int b = blockIdx.x >> 8;
    const int rem = blockIdx.x & 255;
    const int h = rem >> 1;
    const int w0 = (rem & 1) << 6;
    const int wid = tid >> 6;
    const int lane = tid & 63;
    const int ln15 = lane & 15;
    const int quad = lane >> 4;

    // stage 3-row, 66-px window of xT (zero-padded at borders)
    for (int idx = tid; idx < 1584; idx += 256) {
        const int pos = idx >> 3;
        const int part = idx & 7;
        const int r = pos / 66;
        const int xx = pos - r * 66;
        const int y = h + r - 1;
        const int xg = w0 + xx - 1;
        uint4 v = make_uint4(0u, 0u, 0u, 0u);
        if (y >= 0 && y < IH && xg >= 0 && xg < IW)
            v = *(const uint4*)(xT + (((size_t)b << 20) + (((y << 7) + xg) << 6) + (part << 3)));
        *(uint4*)&win[pos * 72 + part * 8] = v;
    }
    // stage weights k=0
    {
        const int o = tid >> 3;
        const int part = tid & 7;
        *(uint4*)&wks[0][o * 72 + part * 8] =
            *(const uint4*)(wt_om16 + (o << 6) + (part << 3));
    }
    __syncthreads();

    f32x4 acc[2] = {{0.f, 0.f, 0.f, 0.f}, {0.f, 0.f, 0.f, 0.f}};

    for (int k = 0; k < 9; ++k) {
        const int buf = k & 1;
        if (k < 8) {   // stage next weight slice into other buffer
            const int o = tid >> 3;
            const int part = tid & 7;
            *(uint4*)&wks[buf ^ 1][o * 72 + part * 8] =
                *(const uint4*)(wt_om16 + ((k + 1) << 11) + (o << 6) + (part << 3));
        }
        const int kh = k / 3;
        const int kw = k - kh * 3;
        const int posb = kh * 66 + wid * 16 + ln15 + kw;
        const unsigned short* wb = wks[buf];
#pragma unroll
        for (int ch = 0; ch < 2; ++ch) {
            const int c = (ch << 5) + (quad << 3);
            U4B8 a, b0, b1;
            a.u  = *(const uint4*)&win[posb * 72 + c];
            b0.u = *(const uint4*)&wb[ln15 * 72 + c];
            b1.u = *(const uint4*)&wb[(16 + ln15) * 72 + c];
            acc[0] = __builtin_amdgcn_mfma_f32_16x16x32_bf16(a.h, b0.h, acc[0], 0, 0, 0);
            acc[1] = __builtin_amdgcn_mfma_f32_16x16x32_bf16(a.h, b1.h, acc[1], 0, 0, 0);
        }
        __syncthreads();
    }

    // C/D layout: col(o)=lane&15, row(px)=quad*4+reg
    const int px0 = wid * 16 + quad * 4;
#pragma unroll
    for (int ot = 0; ot < 2; ++ot) {
        const int o = (ot << 4) + ln15;
        if (o >= 27) continue;
        const float bias = b_om[o];
        float4 r;
        r.x = acc[ot][0] + bias;
        r.y = acc[ot][1] + bias;
        r.z = acc[ot][2] + bias;
        r.w = acc[ot][3] + bias;
        if (o >= 18) {
            r.x = 2.0f / (1.0f + __expf(-r.x));
            r.y = 2.0f / (1.0f + __expf(-r.y));
            r.z = 2.0f / (1.0f + __expf(-r.z));
            r.w = 2.0f / (1.0f + __expf(-r.w));
        }
        *(float4*)&offm[(((size_t)(b * 27 + o)) << 14) + (h << 7) + w0 + px0] = r;
    }
}

// ---------------------------------------------------------------------------
// bilinear corner: accumulate 8+8 channels (frag0 at p, frag1 at p+32)
// ---------------------------------------------------------------------------
__device__ __forceinline__ void corner2(const unsigned short* __restrict__ p,
                                        float wgt, float* v) {
    const uint4 a = *(const uint4*)p;
    const uint4 c = *(const uint4*)(p + 32);
    unsigned int u[8] = {a.x, a.y, a.z, a.w, c.x, c.y, c.z, c.w};
#pragma unroll
    for (int i = 0; i < 8; ++i) {
        v[2 * i]     += wgt * __uint_as_float(u[i] << 16);
        v[2 * i + 1] += wgt * __uint_as_float(u[i] & 0xffff0000u);
    }
}

// ---------------------------------------------------------------------------
// gather one pixel's A-fragments for kernel tap k (registers, no LDS)
// ---------------------------------------------------------------------------
__device__ __forceinline__ void gather_frags(
        const unsigned short* __restrict__ xb, const float* __restrict__ offs,
        int k, int lpx, int h, int w0, int quad, U4B8& a0, U4B8& a1) {
    const float offy = offs[(k << 1) * 64 + lpx];
    const float offx = offs[((k << 1) + 1) * 64 + lpx];
    const float msk  = offs[(18 + k) * 64 + lpx];
    const int kh = k / 3;
    const int kw = k - kh * 3;
    const float py  = (float)(h + kh - 1) + offy;
    const float pxf = (float)(w0 + lpx + kw - 1) + offx;
    const float y0f = floorf(py);
    const float x0f = floorf(pxf);
    const float fy = py - y0f;
    const float fx = pxf - x0f;
    const float wy0 = 1.0f - fy, wx0 = 1.0f - fx;
    const float vy0 = (y0f >= 0.0f && y0f <= 127.0f) ? 1.0f : 0.0f;
    const float vy1 = (y0f >= -1.0f && y0f <= 126.0f) ? 1.0f : 0.0f;
    const float vx0 = (x0f >= 0.0f && x0f <= 127.0f) ? 1.0f : 0.0f;
    const float vx1 = (x0f >= -1.0f && x0f <= 126.0f) ? 1.0f : 0.0f;
    const float w00 = wy0 * wx0 * vy0 * vx0;
    const float w01 = wy0 * fx  * vy0 * vx1;
    const float w10 = fy  * wx0 * vy1 * vx0;
    const float w11 = fy  * fx  * vy1 * vx1;
    const int y0i = min(max((int)y0f, 0), 127);
    const int y1i = min(max((int)y0f + 1, 0), 127);
    const int x0i = min(max((int)x0f, 0), 127);
    const int x1i = min(max((int)x0f + 1, 0), 127);

    float v[16];
#pragma unroll
    for (int i = 0; i < 16; ++i) v[i] = 0.0f;
    const int cofs = quad << 3;
    corner2(xb + ((((size_t)((y0i << 7) + x0i)) << 6) + cofs), w00, v);
    corner2(xb + ((((size_t)((y0i << 7) + x1i)) << 6) + cofs), w01, v);
    corner2(xb + ((((size_t)((y1i << 7) + x0i)) << 6) + cofs), w10, v);
    corner2(xb + ((((size_t)((y1i << 7) + x1i)) << 6) + cofs), w11, v);

    unsigned int pk[8];
#pragma unroll
    for (int i = 0; i < 8; ++i) {
        const unsigned int lo = f32_to_bf16(v[2 * i] * msk);
        const unsigned int hi = f32_to_bf16(v[2 * i + 1] * msk);
        pk[i] = lo | (hi << 16);
    }
    a0.u = make_uint4(pk[0], pk[1], pk[2], pk[3]);
    a1.u = make_uint4(pk[4], pk[5], pk[6], pk[7]);
}

// ---------------------------------------------------------------------------
// Kernel 2: deformable conv. Block = 64px x 64o, 4 waves (16px x 64o each).
// A-frags gathered straight into registers (software-pipelined one k ahead);
// B-frags from double-buffered LDS weight slices. ONE barrier per k.
// ---------------------------------------------------------------------------
__global__ __launch_bounds__(256) void deform_mfma(
        const unsigned short* __restrict__ xT,
        const float* __restrict__ b_dc,
        const float* __restrict__ offm,              // [B][27][H][W]
        const unsigned short* __restrict__ wt_dc16,  // [9][64][64] (k,o,c)
        float* __restrict__ out) {
    __shared__ __align__(16) float offs[27 * 64];            // [ch][lpx]
    __shared__ __align__(16) unsigned short wks[2][64 * 72]; // [buf][o][72]

    const int tid = threadIdx.x;
    const int b = blockIdx.x >> 8;
    const int rem = blockIdx.x & 255;
    const int h = rem >> 1;
    const int w0 = (rem & 1) << 6;
    const int wid = tid >> 6;
    const int lane = tid & 63;
    const int ln15 = lane & 15;
    const int quad = lane >> 4;
    const int lpx = (wid << 4) + ln15;   // local pixel this lane gathers/owns

    // stage offsets/masks for the block's 64 pixels
    for (int i = tid; i < 1728; i += 256) {
        const int ch = i >> 6;
        const int px = i & 63;
        offs[i] = offm[(((size_t)(b * 27 + ch)) << 14) + (h << 7) + w0 + px];
    }
    // stage weights k=0 into wks[0]
    for (int s = tid; s < 512; s += 256) {
        const int o = s >> 3;
        const int part = s & 7;
        *(uint4*)&wks[0][o * 72 + part * 8] =
            *(const uint4*)(wt_dc16 + (o << 6) + (part << 3));
    }
    __syncthreads();

    const unsigned short* xb = xT + ((size_t)b << 20);

    f32x4 acc[4];
#pragma unroll
    for (int i = 0; i < 4; ++i) acc[i] = (f32x4){0.f, 0.f, 0.f, 0.f};

    U4B8 a0c, a1c;
    gather_frags(xb, offs, 0, lpx, h, w0, quad, a0c, a1c);

    for (int k = 0; k < 9; ++k) {
        const int buf = k & 1;
        U4B8 a0n, a1n;
        a0n.u = make_uint4(0u, 0u, 0u, 0u);
        a1n.u = make_uint4(0u, 0u, 0u, 0u);
        if (k < 8) {
            // stage next weight slice (independent of this k's MFMA)
            for (int s = tid; s < 512; s += 256) {
                const int o = s >> 3;
                const int part = s & 7;
                *(uint4*)&wks[buf ^ 1][o * 72 + part * 8] =
                    *(const uint4*)(wt_dc16 + ((k + 1) << 12) + (o << 6) + (part << 3));
            }
            // prefetch next gather into registers
            gather_frags(xb, offs, k + 1, lpx, h, w0, quad, a0n, a1n);
        }
        // MFMA for this k from current regs + LDS weight broadcast
        const unsigned short* wb = wks[buf];
#pragma unroll
        for (int ot = 0; ot < 4; ++ot) {
            U4B8 b0, b1;
            const unsigned short* base = &wb[((ot << 4) + ln15) * 72 + (quad << 3)];
            b0.u = *(const uint4*)base;
            b1.u = *(const uint4*)(base + 32);
            acc[ot] = __builtin_amdgcn_mfma_f32_16x16x32_bf16(a0c.h, b0.h, acc[ot], 0, 0, 0);
            acc[ot] = __builtin_amdgcn_mfma_f32_16x16x32_bf16(a1c.h, b1.h, acc[ot], 0, 0, 0);
        }
        __syncthreads();
        a0c = a0n;
        a1c = a1n;
    }

    // epilogue: col(o)=lane&15, row(px)=quad*4+reg
#pragma unroll
    for (int ot = 0; ot < 4; ++ot) {
        const int o = (ot << 4) + ln15;
        const float bias = b_dc[o];
        float4 r;
        r.x = acc[ot][0] + bias;
        r.y = acc[ot][1] + bias;
        r.z = acc[ot][2] + bias;
        r.w = acc[ot][3] + bias;
        *(float4*)&out[(((size_t)(b * 64 + o)) << 14) + (h << 7) + w0 + (wid << 4) + (quad << 2)] = r;
    }
}

extern "C" void kernel_launch(void* const* d_in, const int* in_sizes, int n_in,
                              void* d_out, int out_size, void* d_ws, size_t ws_size,
                              hipStream_t stream) {
    const float* x    = (const float*)d_in[0];
    const float* w_om = (const float*)d_in[1];
    const float* b_om = (const float*)d_in[2];
    const float* w_dc = (const float*)d_in[3];
    const float* b_dc = (const float*)d_in[4];
    float* out = (float*)d_out;
    float* ws  = (float*)d_ws;

    float* offm = ws + OFFM_OFF;
    unsigned short* xT      = (unsigned short*)(ws + XT_OFF);
    unsigned short* wt_dc16 = (unsigned short*)(ws + WTDC_OFF);
    unsigned short* wt_om16 = (unsigned short*)(ws + WTOM_OFF);

    // 64-px blocks: NB*IH*(IW/64) = 2048 blocks
    const int n_blocks = NB * IH * (IW / 64);

    transpose_weights<<<144, 256, 0, stream>>>(w_dc, w_om, wt_dc16, wt_om16);
    transpose_x<<<NB * IH * 2, 256, 0, stream>>>(x, xT);
    conv_om_mfma<<<n_blocks, 256, 0, stream>>>(xT, b_om, wt_om16, offm);
    deform_mfma<<<n_blocks, 256, 0, stream>>>(xT, b_dc, offm, wt_dc16, out);
}